// Round 8
// baseline (453.984 us; speedup 1.0000x reference)
//
#include <hip/hip_runtime.h>
#include <hip/hip_fp16.h>

#define N_NODES 100000
#define N_EDGES 1250000
#define HID 64
#define N_GRAPHS 512
#define OUT_CH 16

#define BK_NODES 64
#define NBUCKET ((N_NODES + BK_NODES - 1) / BK_NODES)  // 1563
#define NREP 8          // cursor replicas
#define SEG_CAP 192     // per-segment cap: mean 100, sigma 9.4 -> +9.8σ
#define BK_STRIDE (NREP * SEG_CAP)  // 1536 ints per bucket
#define ROWPAD 65       // LDS row stride (floats): bank = (row+k)%32, 2-way free

typedef _Float16 h16;
typedef _Float16 half2_t __attribute__((ext_vector_type(2)));

__device__ __forceinline__ void acc2(unsigned int u, float& a0, float& a1) {
    half2_t h = __builtin_bit_cast(half2_t, u);
    a0 += (float)h[0];
    a1 += (float)h[1];
}

// ===========================================================================
// Partition edges into 64-node dst buckets, 8-way replicated cursors.
// Known floor (r5-r7): scattered-request pipe, ~66 µs. Unchanged.
// ===========================================================================
__global__ __launch_bounds__(256) void k_partition(const int* __restrict__ src,
                                                   const int* __restrict__ dst,
                                                   int* __restrict__ cnt,
                                                   int* __restrict__ buckets) {
    int rep = blockIdx.x & (NREP - 1);
    int i = blockIdx.x * blockDim.x + threadIdx.x;
    int stride = gridDim.x * blockDim.x;
    for (; i < N_EDGES; i += stride) {
        int s = src[i];
        int d = dst[i];
        int b = d >> 6;
        int pos = atomicAdd(&cnt[b * NREP + rep], 1);
        if (pos < SEG_CAP)
            buckets[(size_t)b * BK_STRIDE + rep * SEG_CAP + pos] = ((d & 63) << 17) | s;
    }
}

// ===========================================================================
// Merge the 8 segments of each bucket, sort by dstLocal in LDS, write back
// compacted + bucket-local rowptr [65]. Unchanged.
// ===========================================================================
__global__ __launch_bounds__(256) void k_bucket_sort(const int* __restrict__ cnt,
                                                     int* __restrict__ buckets,
                                                     int* __restrict__ rowptrL) {
    __shared__ int srt[BK_STRIDE];
    __shared__ int hist[BK_NODES];
    __shared__ int curs[BK_NODES];
    int b = blockIdx.x, t = threadIdx.x;
    int* gb = buckets + (size_t)b * BK_STRIDE;
    int c[NREP];
#pragma unroll
    for (int r = 0; r < NREP; ++r) {
        int x = cnt[b * NREP + r];
        c[r] = x < SEG_CAP ? x : SEG_CAP;
    }
    if (t < BK_NODES) hist[t] = 0;
    __syncthreads();
#pragma unroll
    for (int r = 0; r < NREP; ++r)
        for (int i = t; i < c[r]; i += 256)
            atomicAdd(&hist[gb[r * SEG_CAP + i] >> 17], 1);
    __syncthreads();
    if (t < 64) {
        int h = hist[t];
        int x = h;
        for (int off = 1; off < 64; off <<= 1) {
            int u = __shfl_up(x, off, 64);
            if (t >= off) x += u;
        }
        curs[t] = x - h;
        rowptrL[b * 65 + t] = x - h;
        if (t == 63) rowptrL[b * 65 + 64] = x;
    }
    __syncthreads();
#pragma unroll
    for (int r = 0; r < NREP; ++r)
        for (int i = t; i < c[r]; i += 256) {
            int rec = gb[r * SEG_CAP + i];
            int pos = atomicAdd(&curs[rec >> 17], 1);
            srt[pos] = rec;
        }
    __syncthreads();
    int n = 0;
#pragma unroll
    for (int r = 0; r < NREP; ++r) n += c[r];
    for (int i = t; i < n; i += 256) gb[i] = srt[i];
}

// ===========================================================================
// Aggregate (r7, at its L3-random-access floor ~160MB/layer): unchanged.
// ===========================================================================
__global__ __launch_bounds__(256) void k_aggregate(const int* __restrict__ rowptrL,
                                                   const int* __restrict__ buckets,
                                                   const h16* __restrict__ H,
                                                   h16* __restrict__ Z) {
    const unsigned int* H2 = (const unsigned int*)H;
    unsigned int* Z2 = (unsigned int*)Z;
    int lane = threadIdx.x & 63;
    int half = lane >> 5, sub = lane & 31;
    int gwave = (blockIdx.x * 256 + threadIdx.x) >> 6;
    int nw = (gridDim.x * 256) >> 6;
    for (int i = gwave; i < N_NODES; i += nw) {
        int b = i >> 6, local = i & 63;
        int start = rowptrL[b * 65 + local], end = rowptrL[b * 65 + local + 1];
        const int* bk = buckets + (size_t)b * BK_STRIDE;
        float a0 = 0.f, a1 = 0.f;
        if (half == 0) acc2(H2[(size_t)i * 32 + sub], a0, a1);
        int j = start;
        for (; j + 4 <= end; j += 4) {
            int sA = bk[j + half] & 0x1FFFF;
            int sB = bk[j + 2 + half] & 0x1FFFF;
            unsigned int uA = H2[(size_t)sA * 32 + sub];
            unsigned int uB = H2[(size_t)sB * 32 + sub];
            acc2(uA, a0, a1);
            acc2(uB, a0, a1);
        }
        if (j + 1 < end) {
            int s = bk[j + half] & 0x1FFFF;
            acc2(H2[(size_t)s * 32 + sub], a0, a1);
            j += 2;
        }
        if (j < end && half == 0) {
            int s = bk[j] & 0x1FFFF;
            acc2(H2[(size_t)s * 32 + sub], a0, a1);
        }
        a0 += __shfl_xor(a0, 32, 64);
        a1 += __shfl_xor(a1, 32, 64);
        if (half == 0) {
            half2_t o;
            o[0] = (h16)a0;
            o[1] = (h16)a1;
            Z2[(size_t)i * 32 + sub] = __builtin_bit_cast(unsigned int, o);
        }
    }
}

// ===========================================================================
// NEW MLP (r8): lane = row, wave = 16-col strip. A-row in VGPRs (direct
// global read), weights via wave-uniform SCALAR loads (s_load, not DS),
// per k: 16 v_fma with SGPR operand -> VALU-bound (~10 µs floor).
// Only the GEMM1->GEMM2 transpose goes through LDS (stride-65, 2-way free).
// Epilogue repacks through LDS (stride-33) for coalesced fp16 stores.
// ===========================================================================
__global__ __launch_bounds__(256) void k_mlp(const float* __restrict__ Wa,
                                             const float* __restrict__ Ba,
                                             const float* __restrict__ Wb,
                                             const float* __restrict__ Bb,
                                             const h16* __restrict__ Zin,
                                             h16* __restrict__ Hout) {
    __shared__ float sT[64 * ROWPAD];   // T[row][mid], padded; reused as sOut
    int t = threadIdx.x;
    int lane = t & 63;                  // row within 64-row tile
    int wv = t >> 6;                    // 0..3
    int tcw = __builtin_amdgcn_readfirstlane(wv);  // force wave-uniform
    int row0 = blockIdx.x * 64;
    int row = row0 + lane;
    int rrow = row < N_NODES ? row : 0;

    // lane's Z row: 64 fp16 = 8 uint4 -> 32 dwords in registers
    unsigned ad[32];
    {
        const uint4* zr = (const uint4*)(Zin + (size_t)rrow * HID);
#pragma unroll
        for (int i = 0; i < 8; ++i) {
            uint4 v = zr[i];
            ad[4 * i + 0] = v.x; ad[4 * i + 1] = v.y;
            ad[4 * i + 2] = v.z; ad[4 * i + 3] = v.w;
        }
    }

    // GEMM1: acc[q] = Ba[c] + sum_k Z[row][k] * Wa[k][c], c = 16*tcw+q
    float acc[16];
#pragma unroll
    for (int q = 0; q < 16; ++q) acc[q] = Ba[16 * tcw + q];  // scalar loads
#pragma unroll
    for (int kk = 0; kk < 32; ++kk) {
        half2_t h2 = __builtin_bit_cast(half2_t, ad[kk]);
        float a0 = (float)h2[0];
        float a1 = (float)h2[1];
        const float* w0 = Wa + (2 * kk) * HID + 16 * tcw;    // uniform -> s_load
        const float* w1 = w0 + HID;
#pragma unroll
        for (int q = 0; q < 16; ++q) acc[q] = fmaf(a0, w0[q], acc[q]);
#pragma unroll
        for (int q = 0; q < 16; ++q) acc[q] = fmaf(a1, w1[q], acc[q]);
    }

    // T = relu(acc) -> LDS (lane writes its own row's 16 mids)
#pragma unroll
    for (int q = 0; q < 16; ++q)
        sT[lane * ROWPAD + 16 * wv + q] = fmaxf(acc[q], 0.f);
    __syncthreads();

    // GEMM2: acc[q] = Bb[c] + sum_m T[row][m] * Wb[m][c]
#pragma unroll
    for (int q = 0; q < 16; ++q) acc[q] = Bb[16 * tcw + q];
#pragma unroll 16
    for (int m = 0; m < 64; ++m) {
        float tv = sT[lane * ROWPAD + m];                    // b32, 2-way free
        const float* w = Wb + m * HID + 16 * tcw;            // uniform -> s_load
#pragma unroll
        for (int q = 0; q < 16; ++q) acc[q] = fmaf(tv, w[q], acc[q]);
    }
    __syncthreads();  // all sT reads done before overwrite

    // epilogue: pack fp16 pairs into LDS (stride 33), then coalesced stores
    unsigned* sO = (unsigned*)sT;
#pragma unroll
    for (int q = 0; q < 8; ++q) {
        half2_t o;
        o[0] = (h16)fmaxf(acc[2 * q + 0], 0.f);
        o[1] = (h16)fmaxf(acc[2 * q + 1], 0.f);
        sO[lane * 33 + 8 * wv + q] = __builtin_bit_cast(unsigned, o);
    }
    __syncthreads();
    {
        int rowL = t >> 2, seg = t & 3;
        int grow = row0 + rowL;
        if (grow < N_NODES) {
            unsigned* dst = (unsigned*)Hout + (size_t)grow * 32 + seg * 8;
            uint4 o1, o2;
            o1.x = sO[rowL * 33 + seg * 8 + 0];
            o1.y = sO[rowL * 33 + seg * 8 + 1];
            o1.z = sO[rowL * 33 + seg * 8 + 2];
            o1.w = sO[rowL * 33 + seg * 8 + 3];
            o2.x = sO[rowL * 33 + seg * 8 + 4];
            o2.y = sO[rowL * 33 + seg * 8 + 5];
            o2.z = sO[rowL * 33 + seg * 8 + 6];
            o2.w = sO[rowL * 33 + seg * 8 + 7];
            *(uint4*)dst = o1;
            *(uint4*)(dst + 4) = o2;
        }
    }
}

// ===========================================================================
// NEW input linear (r8): same template, fp32 A-row (64 floats in VGPRs).
// ===========================================================================
__global__ __launch_bounds__(256) void k_lin(const float* __restrict__ W,
                                             const float* __restrict__ B,
                                             const float* __restrict__ Xin,
                                             h16* __restrict__ Hout) {
    __shared__ unsigned sO[64 * 33];
    int t = threadIdx.x;
    int lane = t & 63;
    int wv = t >> 6;
    int tcw = __builtin_amdgcn_readfirstlane(wv);
    int row0 = blockIdx.x * 64;
    int row = row0 + lane;
    int rrow = row < N_NODES ? row : 0;

    float af[64];
    {
        const float4* xr = (const float4*)(Xin + (size_t)rrow * HID);
#pragma unroll
        for (int i = 0; i < 16; ++i) {
            float4 v = xr[i];
            af[4 * i + 0] = v.x; af[4 * i + 1] = v.y;
            af[4 * i + 2] = v.z; af[4 * i + 3] = v.w;
        }
    }

    float acc[16];
#pragma unroll
    for (int q = 0; q < 16; ++q) acc[q] = B[16 * tcw + q];
#pragma unroll
    for (int k = 0; k < 64; ++k) {
        float a = af[k];
        const float* w = W + k * HID + 16 * tcw;
#pragma unroll
        for (int q = 0; q < 16; ++q) acc[q] = fmaf(a, w[q], acc[q]);
    }

#pragma unroll
    for (int q = 0; q < 8; ++q) {
        half2_t o;
        o[0] = (h16)fmaxf(acc[2 * q + 0], 0.f);
        o[1] = (h16)fmaxf(acc[2 * q + 1], 0.f);
        sO[lane * 33 + 8 * wv + q] = __builtin_bit_cast(unsigned, o);
    }
    __syncthreads();
    {
        int rowL = t >> 2, seg = t & 3;
        int grow = row0 + rowL;
        if (grow < N_NODES) {
            unsigned* dst = (unsigned*)Hout + (size_t)grow * 32 + seg * 8;
            uint4 o1, o2;
            o1.x = sO[rowL * 33 + seg * 8 + 0];
            o1.y = sO[rowL * 33 + seg * 8 + 1];
            o1.z = sO[rowL * 33 + seg * 8 + 2];
            o1.w = sO[rowL * 33 + seg * 8 + 3];
            o2.x = sO[rowL * 33 + seg * 8 + 4];
            o2.y = sO[rowL * 33 + seg * 8 + 5];
            o2.z = sO[rowL * 33 + seg * 8 + 6];
            o2.w = sO[rowL * 33 + seg * 8 + 7];
            *(uint4*)dst = o1;
            *(uint4*)(dst + 4) = o2;
        }
    }
}

// ===========================================================================
// Mean-pool: block (4 waves) per graph; batch sorted -> binary search.
// ===========================================================================
__global__ __launch_bounds__(256) void k_pool(const h16* __restrict__ H,
                                              const int* __restrict__ batch,
                                              float* __restrict__ pooled) {
    __shared__ float sp[4 * HID];
    int g = blockIdx.x;
    int lane = threadIdx.x & 63, w = threadIdx.x >> 6;
    int lo = 0, hi = N_NODES;
    while (lo < hi) { int m = (lo + hi) >> 1; if (batch[m] < g) lo = m + 1; else hi = m; }
    int start = lo;
    hi = N_NODES;
    while (lo < hi) { int m = (lo + hi) >> 1; if (batch[m] < g + 1) lo = m + 1; else hi = m; }
    int end = lo;
    float s = 0.f;
    for (int r = start + w; r < end; r += 4) s += (float)H[(size_t)r * HID + lane];
    sp[w * HID + lane] = s;
    __syncthreads();
    if (w == 0) {
        float tot = sp[lane] + sp[HID + lane] + sp[2 * HID + lane] + sp[3 * HID + lane];
        float c = (end > start) ? (float)(end - start) : 1.0f;
        pooled[g * HID + lane] = tot / c;
    }
}

__global__ __launch_bounds__(64) void k_final(const float* __restrict__ pooled,
                                              const float* __restrict__ Wl,
                                              const float* __restrict__ bl,
                                              float* __restrict__ out) {
    __shared__ float sp[HID];
    int g = blockIdx.x, lane = threadIdx.x;
    sp[lane] = pooled[g * HID + lane];
    __syncthreads();
    if (lane < OUT_CH) {
        float acc = bl[lane];
#pragma unroll
        for (int k = 0; k < HID; ++k) acc += sp[k] * Wl[k * OUT_CH + lane];
        out[g * OUT_CH + lane] = acc;
    }
}

extern "C" void kernel_launch(void* const* d_in, const int* in_sizes, int n_in,
                              void* d_out, int out_size, void* d_ws, size_t ws_size,
                              hipStream_t stream) {
    const float* x     = (const float*)d_in[0];
    const int*   edge  = (const int*)d_in[1];   // [2][N_EDGES] int32
    const int*   batch = (const int*)d_in[2];   // [N_NODES] int32 (sorted)
    const float* W0  = (const float*)d_in[3];
    const float* b0  = (const float*)d_in[4];
    const float* W1a = (const float*)d_in[5];
    const float* b1a = (const float*)d_in[6];
    const float* W1b = (const float*)d_in[7];
    const float* b1b = (const float*)d_in[8];
    const float* W2a = (const float*)d_in[9];
    const float* b2a = (const float*)d_in[10];
    const float* W2b = (const float*)d_in[11];
    const float* b2b = (const float*)d_in[12];
    const float* W3a = (const float*)d_in[13];
    const float* b3a = (const float*)d_in[14];
    const float* W3b = (const float*)d_in[15];
    const float* b3b = (const float*)d_in[16];
    const float* Wl  = (const float*)d_in[17];
    const float* bl  = (const float*)d_in[18];
    float* out = (float*)d_out;

    const int* src = edge;
    const int* dst = edge + N_EDGES;

    // Workspace: HA(fp16) | Z(fp16) | pooled | cnt | rowptrL | buckets
    h16*   HA     = (h16*)d_ws;
    h16*   Z      = HA + (size_t)N_NODES * HID;
    float* pooled = (float*)(Z + (size_t)N_NODES * HID);
    int*   cnt     = (int*)(pooled + (size_t)N_GRAPHS * HID);
    int*   rowptrL = cnt + NBUCKET * NREP;
    int*   buckets = rowptrL + NBUCKET * 65;

    const int TILE_BLOCKS = (N_NODES + 63) / 64;  // 1563

    hipMemsetAsync(cnt, 0, NBUCKET * NREP * sizeof(int), stream);
    k_partition<<<4096, 256, 0, stream>>>(src, dst, cnt, buckets);
    k_bucket_sort<<<NBUCKET, 256, 0, stream>>>(cnt, buckets, rowptrL);

    k_lin<<<TILE_BLOCKS, 256, 0, stream>>>(W0, b0, x, HA);

    k_aggregate<<<2048, 256, 0, stream>>>(rowptrL, buckets, HA, Z);
    k_mlp<<<TILE_BLOCKS, 256, 0, stream>>>(W1a, b1a, W1b, b1b, Z, HA);

    k_aggregate<<<2048, 256, 0, stream>>>(rowptrL, buckets, HA, Z);
    k_mlp<<<TILE_BLOCKS, 256, 0, stream>>>(W2a, b2a, W2b, b2b, Z, HA);

    k_aggregate<<<2048, 256, 0, stream>>>(rowptrL, buckets, HA, Z);
    k_mlp<<<TILE_BLOCKS, 256, 0, stream>>>(W3a, b3a, W3b, b3b, Z, HA);

    k_pool<<<N_GRAPHS, 256, 0, stream>>>(HA, batch, pooled);
    k_final<<<N_GRAPHS, 64, 0, stream>>>(pooled, Wl, bl, out);
}

// Round 9
// 449.785 us; speedup vs baseline: 1.0093x; 1.0093x over previous
//
#include <hip/hip_runtime.h>
#include <hip/hip_fp16.h>

#define N_NODES 100000
#define N_EDGES 1250000
#define HID 64
#define N_GRAPHS 512
#define OUT_CH 16

#define BK_NODES 64
#define NBUCKET ((N_NODES + BK_NODES - 1) / BK_NODES)  // 1563
#define NREP 8          // cursor replicas
#define SEG_CAP 192     // per-segment cap: mean 100, sigma 9.4 -> +9.8σ
#define BK_STRIDE (NREP * SEG_CAP)  // 1536 ints per bucket
#define TILE2 ((N_NODES + 127) / 128)  // 782 blocks for 128-row GEMM tiles

typedef _Float16 h16;
typedef _Float16 half2_t __attribute__((ext_vector_type(2)));

__device__ __forceinline__ void acc2(unsigned int u, float& a0, float& a1) {
    half2_t h = __builtin_bit_cast(half2_t, u);
    a0 += (float)h[0];
    a1 += (float)h[1];
}

__device__ __forceinline__ unsigned pack2(float x, float y) {
    half2_t o;
    o[0] = (h16)x;
    o[1] = (h16)y;
    return __builtin_bit_cast(unsigned, o);
}

// ===========================================================================
// Partition edges into 64-node dst buckets, 8-way replicated cursors.
// Known floor (r5-r8): scattered-request pipe, ~66 µs. Unchanged.
// ===========================================================================
__global__ __launch_bounds__(256) void k_partition(const int* __restrict__ src,
                                                   const int* __restrict__ dst,
                                                   int* __restrict__ cnt,
                                                   int* __restrict__ buckets) {
    int rep = blockIdx.x & (NREP - 1);
    int i = blockIdx.x * blockDim.x + threadIdx.x;
    int stride = gridDim.x * blockDim.x;
    for (; i < N_EDGES; i += stride) {
        int s = src[i];
        int d = dst[i];
        int b = d >> 6;
        int pos = atomicAdd(&cnt[b * NREP + rep], 1);
        if (pos < SEG_CAP)
            buckets[(size_t)b * BK_STRIDE + rep * SEG_CAP + pos] = ((d & 63) << 17) | s;
    }
}

// ===========================================================================
// Merge the 8 segments of each bucket, sort by dstLocal in LDS, write back
// compacted + bucket-local rowptr [65]. Unchanged.
// ===========================================================================
__global__ __launch_bounds__(256) void k_bucket_sort(const int* __restrict__ cnt,
                                                     int* __restrict__ buckets,
                                                     int* __restrict__ rowptrL) {
    __shared__ int srt[BK_STRIDE];
    __shared__ int hist[BK_NODES];
    __shared__ int curs[BK_NODES];
    int b = blockIdx.x, t = threadIdx.x;
    int* gb = buckets + (size_t)b * BK_STRIDE;
    int c[NREP];
#pragma unroll
    for (int r = 0; r < NREP; ++r) {
        int x = cnt[b * NREP + r];
        c[r] = x < SEG_CAP ? x : SEG_CAP;
    }
    if (t < BK_NODES) hist[t] = 0;
    __syncthreads();
#pragma unroll
    for (int r = 0; r < NREP; ++r)
        for (int i = t; i < c[r]; i += 256)
            atomicAdd(&hist[gb[r * SEG_CAP + i] >> 17], 1);
    __syncthreads();
    if (t < 64) {
        int h = hist[t];
        int x = h;
        for (int off = 1; off < 64; off <<= 1) {
            int u = __shfl_up(x, off, 64);
            if (t >= off) x += u;
        }
        curs[t] = x - h;
        rowptrL[b * 65 + t] = x - h;
        if (t == 63) rowptrL[b * 65 + 64] = x;
    }
    __syncthreads();
#pragma unroll
    for (int r = 0; r < NREP; ++r)
        for (int i = t; i < c[r]; i += 256) {
            int rec = gb[r * SEG_CAP + i];
            int pos = atomicAdd(&curs[rec >> 17], 1);
            srt[pos] = rec;
        }
    __syncthreads();
    int n = 0;
#pragma unroll
    for (int r = 0; r < NREP; ++r) n += c[r];
    for (int i = t; i < n; i += 256) gb[i] = srt[i];
}

// ===========================================================================
// Aggregate (r7 form, at its L3-random-line floor): unchanged code; grid
// bumped 2048->4096 for tail balance (same lever that won in partition).
// ===========================================================================
__global__ __launch_bounds__(256) void k_aggregate(const int* __restrict__ rowptrL,
                                                   const int* __restrict__ buckets,
                                                   const h16* __restrict__ H,
                                                   h16* __restrict__ Z) {
    const unsigned int* H2 = (const unsigned int*)H;
    unsigned int* Z2 = (unsigned int*)Z;
    int lane = threadIdx.x & 63;
    int half = lane >> 5, sub = lane & 31;
    int gwave = (blockIdx.x * 256 + threadIdx.x) >> 6;
    int nw = (gridDim.x * 256) >> 6;
    for (int i = gwave; i < N_NODES; i += nw) {
        int b = i >> 6, local = i & 63;
        int start = rowptrL[b * 65 + local], end = rowptrL[b * 65 + local + 1];
        const int* bk = buckets + (size_t)b * BK_STRIDE;
        float a0 = 0.f, a1 = 0.f;
        if (half == 0) acc2(H2[(size_t)i * 32 + sub], a0, a1);
        int j = start;
        for (; j + 4 <= end; j += 4) {
            int sA = bk[j + half] & 0x1FFFF;
            int sB = bk[j + 2 + half] & 0x1FFFF;
            unsigned int uA = H2[(size_t)sA * 32 + sub];
            unsigned int uB = H2[(size_t)sB * 32 + sub];
            acc2(uA, a0, a1);
            acc2(uB, a0, a1);
        }
        if (j + 1 < end) {
            int s = bk[j + half] & 0x1FFFF;
            acc2(H2[(size_t)s * 32 + sub], a0, a1);
            j += 2;
        }
        if (j < end && half == 0) {
            int s = bk[j] & 0x1FFFF;
            acc2(H2[(size_t)s * 32 + sub], a0, a1);
        }
        a0 += __shfl_xor(a0, 32, 64);
        a1 += __shfl_xor(a1, 32, 64);
        if (half == 0) Z2[(size_t)i * 32 + sub] = pack2(a0, a1);
    }
}

// ===========================================================================
// MLP r9: 128-row tile, 8x4 register blocking. Per k a wave issues 3
// ds_read_b128 (A rows {4tr, 64+4tr} keep 16B lane stride -> 2-way free)
// for 32 FMA -> DS instr/row 8->6 vs r7; LDS 48 KB -> 3 blocks/CU.
// ===========================================================================
__global__ __launch_bounds__(256) void k_mlp(const float* __restrict__ Wa,
                                             const float* __restrict__ Ba,
                                             const float* __restrict__ Wb,
                                             const float* __restrict__ Bb,
                                             const h16* __restrict__ Zin,
                                             h16* __restrict__ Hout) {
    __shared__ float sA[64 * 128];  // [k][row], 32 KB (also holds T for GEMM2)
    __shared__ float sW[64 * 64];   // [k][col], 16 KB
    int t = threadIdx.x;
    int row0 = blockIdx.x * 128;

#pragma unroll
    for (int i = 0; i < 16; ++i) sW[t + 256 * i] = Wa[t + 256 * i];
    // stage Z transposed: thread = (row t>>1, k-half (t&1)*32); 2-way free
    {
        int rowL = t >> 1, kh = (t & 1) * 32;
        int grow = row0 + rowL;
        bool valid = grow < N_NODES;
        const uint4* zr = (const uint4*)((const unsigned*)Zin +
                                         (size_t)(valid ? grow : 0) * 32 + kh / 2);
#pragma unroll
        for (int c = 0; c < 4; ++c) {
            uint4 v = zr[c];
            unsigned u[4] = {v.x, v.y, v.z, v.w};
#pragma unroll
            for (int p = 0; p < 4; ++p) {
                half2_t h = __builtin_bit_cast(half2_t, u[p]);
                int k = kh + 8 * c + 2 * p;
                sA[k * 128 + rowL] = valid ? (float)h[0] : 0.f;
                sA[(k + 1) * 128 + rowL] = valid ? (float)h[1] : 0.f;
            }
        }
    }
    __syncthreads();

    int tr = t & 15, tc = t >> 4;
    float4 ba4 = *(const float4*)&Ba[4 * tc];
    float4 bb4 = *(const float4*)&Bb[4 * tc];
    float acc[2][4][4];
#pragma unroll
    for (int h = 0; h < 2; ++h)
#pragma unroll
        for (int i = 0; i < 4; ++i) {
            acc[h][i][0] = ba4.x; acc[h][i][1] = ba4.y;
            acc[h][i][2] = ba4.z; acc[h][i][3] = ba4.w;
        }
#pragma unroll 4
    for (int k = 0; k < 64; ++k) {
        float4 a0 = *(const float4*)&sA[k * 128 + 4 * tr];
        float4 a1 = *(const float4*)&sA[k * 128 + 64 + 4 * tr];
        float4 b = *(const float4*)&sW[k * 64 + 4 * tc];
        const float av0[4] = {a0.x, a0.y, a0.z, a0.w};
        const float av1[4] = {a1.x, a1.y, a1.z, a1.w};
        const float bv[4] = {b.x, b.y, b.z, b.w};
#pragma unroll
        for (int i = 0; i < 4; ++i)
#pragma unroll
            for (int j = 0; j < 4; ++j) {
                acc[0][i][j] = fmaf(av0[i], bv[j], acc[0][i][j]);
                acc[1][i][j] = fmaf(av1[i], bv[j], acc[1][i][j]);
            }
    }
    __syncthreads();  // GEMM1 reads done

    // sW <- Wb; sA <- T = relu(acc), layout [mid][row]
#pragma unroll
    for (int i = 0; i < 16; ++i) sW[t + 256 * i] = Wb[t + 256 * i];
#pragma unroll
    for (int h = 0; h < 2; ++h)
#pragma unroll
        for (int i = 0; i < 4; ++i)
#pragma unroll
            for (int j = 0; j < 4; ++j)
                sA[(4 * tc + j) * 128 + h * 64 + 4 * tr + i] =
                    fmaxf(acc[h][i][j], 0.f);
    __syncthreads();

#pragma unroll
    for (int h = 0; h < 2; ++h)
#pragma unroll
        for (int i = 0; i < 4; ++i) {
            acc[h][i][0] = bb4.x; acc[h][i][1] = bb4.y;
            acc[h][i][2] = bb4.z; acc[h][i][3] = bb4.w;
        }
#pragma unroll 4
    for (int k = 0; k < 64; ++k) {
        float4 a0 = *(const float4*)&sA[k * 128 + 4 * tr];
        float4 a1 = *(const float4*)&sA[k * 128 + 64 + 4 * tr];
        float4 b = *(const float4*)&sW[k * 64 + 4 * tc];
        const float av0[4] = {a0.x, a0.y, a0.z, a0.w};
        const float av1[4] = {a1.x, a1.y, a1.z, a1.w};
        const float bv[4] = {b.x, b.y, b.z, b.w};
#pragma unroll
        for (int i = 0; i < 4; ++i)
#pragma unroll
            for (int j = 0; j < 4; ++j) {
                acc[0][i][j] = fmaf(av0[i], bv[j], acc[0][i][j]);
                acc[1][i][j] = fmaf(av1[i], bv[j], acc[1][i][j]);
            }
    }

    // epilogue: direct 8B fp16 stores (4 cols per row)
#pragma unroll
    for (int h = 0; h < 2; ++h)
#pragma unroll
        for (int i = 0; i < 4; ++i) {
            int row = row0 + h * 64 + 4 * tr + i;
            if (row < N_NODES) {
                uint2 o;
                o.x = pack2(fmaxf(acc[h][i][0], 0.f), fmaxf(acc[h][i][1], 0.f));
                o.y = pack2(fmaxf(acc[h][i][2], 0.f), fmaxf(acc[h][i][3], 0.f));
                *(uint2*)((unsigned*)Hout + (size_t)row * 32 + tc * 2) = o;
            }
        }
}

// ===========================================================================
// Input linear r9: same 128-row/8x4 template, fp32 input, single GEMM.
// ===========================================================================
__global__ __launch_bounds__(256) void k_lin(const float* __restrict__ W,
                                             const float* __restrict__ B,
                                             const float* __restrict__ Xin,
                                             h16* __restrict__ Hout) {
    __shared__ float sA[64 * 128];
    __shared__ float sW[64 * 64];
    int t = threadIdx.x;
    int row0 = blockIdx.x * 128;

#pragma unroll
    for (int i = 0; i < 16; ++i) sW[t + 256 * i] = W[t + 256 * i];
    {
        int rowL = t >> 1, kh = (t & 1) * 32;
        int grow = row0 + rowL;
        bool valid = grow < N_NODES;
        const float4* xr = (const float4*)(Xin + (size_t)(valid ? grow : 0) * HID + kh);
#pragma unroll
        for (int c = 0; c < 8; ++c) {
            float4 v = xr[c];
            int k = kh + 4 * c;
            sA[(k + 0) * 128 + rowL] = valid ? v.x : 0.f;
            sA[(k + 1) * 128 + rowL] = valid ? v.y : 0.f;
            sA[(k + 2) * 128 + rowL] = valid ? v.z : 0.f;
            sA[(k + 3) * 128 + rowL] = valid ? v.w : 0.f;
        }
    }
    __syncthreads();

    int tr = t & 15, tc = t >> 4;
    float4 b4 = *(const float4*)&B[4 * tc];
    float acc[2][4][4];
#pragma unroll
    for (int h = 0; h < 2; ++h)
#pragma unroll
        for (int i = 0; i < 4; ++i) {
            acc[h][i][0] = b4.x; acc[h][i][1] = b4.y;
            acc[h][i][2] = b4.z; acc[h][i][3] = b4.w;
        }
#pragma unroll 4
    for (int k = 0; k < 64; ++k) {
        float4 a0 = *(const float4*)&sA[k * 128 + 4 * tr];
        float4 a1 = *(const float4*)&sA[k * 128 + 64 + 4 * tr];
        float4 b = *(const float4*)&sW[k * 64 + 4 * tc];
        const float av0[4] = {a0.x, a0.y, a0.z, a0.w};
        const float av1[4] = {a1.x, a1.y, a1.z, a1.w};
        const float bv[4] = {b.x, b.y, b.z, b.w};
#pragma unroll
        for (int i = 0; i < 4; ++i)
#pragma unroll
            for (int j = 0; j < 4; ++j) {
                acc[0][i][j] = fmaf(av0[i], bv[j], acc[0][i][j]);
                acc[1][i][j] = fmaf(av1[i], bv[j], acc[1][i][j]);
            }
    }
#pragma unroll
    for (int h = 0; h < 2; ++h)
#pragma unroll
        for (int i = 0; i < 4; ++i) {
            int row = row0 + h * 64 + 4 * tr + i;
            if (row < N_NODES) {
                uint2 o;
                o.x = pack2(fmaxf(acc[h][i][0], 0.f), fmaxf(acc[h][i][1], 0.f));
                o.y = pack2(fmaxf(acc[h][i][2], 0.f), fmaxf(acc[h][i][3], 0.f));
                *(uint2*)((unsigned*)Hout + (size_t)row * 32 + tc * 2) = o;
            }
        }
}

// ===========================================================================
// Fused mean-pool + readout: one block per graph; block computes its pooled
// row then its own 16 outputs (saves the k_final launch + pooled round-trip).
// ===========================================================================
__global__ __launch_bounds__(256) void k_poolfinal(const h16* __restrict__ H,
                                                   const int* __restrict__ batch,
                                                   const float* __restrict__ Wl,
                                                   const float* __restrict__ bl,
                                                   float* __restrict__ out) {
    __shared__ float sp[4 * HID];
    int g = blockIdx.x;
    int t = threadIdx.x;
    int lane = t & 63, w = t >> 6;
    int lo = 0, hi = N_NODES;
    while (lo < hi) { int m = (lo + hi) >> 1; if (batch[m] < g) lo = m + 1; else hi = m; }
    int start = lo;
    hi = N_NODES;
    while (lo < hi) { int m = (lo + hi) >> 1; if (batch[m] < g + 1) lo = m + 1; else hi = m; }
    int end = lo;
    float s = 0.f;
    for (int r = start + w; r < end; r += 4) s += (float)H[(size_t)r * HID + lane];
    sp[w * HID + lane] = s;
    __syncthreads();
    if (t < HID) {
        float tot = sp[t] + sp[HID + t] + sp[2 * HID + t] + sp[3 * HID + t];
        float c = (end > start) ? (float)(end - start) : 1.0f;
        sp[t] = tot / c;
    }
    __syncthreads();
    if (t < OUT_CH) {
        float acc = bl[t];
#pragma unroll
        for (int k = 0; k < HID; ++k) acc += sp[k] * Wl[k * OUT_CH + t];
        out[g * OUT_CH + t] = acc;
    }
}

extern "C" void kernel_launch(void* const* d_in, const int* in_sizes, int n_in,
                              void* d_out, int out_size, void* d_ws, size_t ws_size,
                              hipStream_t stream) {
    const float* x     = (const float*)d_in[0];
    const int*   edge  = (const int*)d_in[1];   // [2][N_EDGES] int32
    const int*   batch = (const int*)d_in[2];   // [N_NODES] int32 (sorted)
    const float* W0  = (const float*)d_in[3];
    const float* b0  = (const float*)d_in[4];
    const float* W1a = (const float*)d_in[5];
    const float* b1a = (const float*)d_in[6];
    const float* W1b = (const float*)d_in[7];
    const float* b1b = (const float*)d_in[8];
    const float* W2a = (const float*)d_in[9];
    const float* b2a = (const float*)d_in[10];
    const float* W2b = (const float*)d_in[11];
    const float* b2b = (const float*)d_in[12];
    const float* W3a = (const float*)d_in[13];
    const float* b3a = (const float*)d_in[14];
    const float* W3b = (const float*)d_in[15];
    const float* b3b = (const float*)d_in[16];
    const float* Wl  = (const float*)d_in[17];
    const float* bl  = (const float*)d_in[18];
    float* out = (float*)d_out;

    const int* src = edge;
    const int* dst = edge + N_EDGES;

    // Workspace: HA(fp16) | Z(fp16) | cnt | rowptrL | buckets
    h16* HA = (h16*)d_ws;
    h16* Z  = HA + (size_t)N_NODES * HID;
    int* cnt     = (int*)(Z + (size_t)N_NODES * HID);
    int* rowptrL = cnt + NBUCKET * NREP;
    int* buckets = rowptrL + NBUCKET * 65;

    hipMemsetAsync(cnt, 0, NBUCKET * NREP * sizeof(int), stream);
    k_partition<<<4096, 256, 0, stream>>>(src, dst, cnt, buckets);
    k_bucket_sort<<<NBUCKET, 256, 0, stream>>>(cnt, buckets, rowptrL);

    k_lin<<<TILE2, 256, 0, stream>>>(W0, b0, x, HA);

    k_aggregate<<<4096, 256, 0, stream>>>(rowptrL, buckets, HA, Z);
    k_mlp<<<TILE2, 256, 0, stream>>>(W1a, b1a, W1b, b1b, Z, HA);

    k_aggregate<<<4096, 256, 0, stream>>>(rowptrL, buckets, HA, Z);
    k_mlp<<<TILE2, 256, 0, stream>>>(W2a, b2a, W2b, b2b, Z, HA);

    k_aggregate<<<4096, 256, 0, stream>>>(rowptrL, buckets, HA, Z);
    k_mlp<<<TILE2, 256, 0, stream>>>(W3a, b3a, W3b, b3b, Z, HA);

    k_poolfinal<<<N_GRAPHS, 256, 0, stream>>>(HA, batch, Wl, bl, out);
}

// Round 10
// 388.343 us; speedup vs baseline: 1.1690x; 1.1582x over previous
//
#include <hip/hip_runtime.h>
#include <hip/hip_fp16.h>

#define N_NODES 100000
#define N_EDGES 1250000
#define HID 64
#define N_GRAPHS 512
#define OUT_CH 16

#define BK_NODES 64
#define NBUCKET ((N_NODES + BK_NODES - 1) / BK_NODES)  // 1563
#define NREP 8          // cursor replicas
#define SEG_CAP 192     // per-segment cap: mean 100, sigma 9.4 -> +9.8σ
#define BK_STRIDE (NREP * SEG_CAP)  // 1536 ints per bucket
#define TILE1 ((N_NODES + 63) / 64)  // 1563 blocks, 64-row MFMA tiles
#define TSTRIDE 68      // LDS T row stride (floats): 16B-aligned, writes 2-way

typedef _Float16 h16;
typedef _Float16 half2_t __attribute__((ext_vector_type(2)));
typedef _Float16 f16x8 __attribute__((ext_vector_type(8)));
typedef float f32x4 __attribute__((ext_vector_type(4)));

__device__ __forceinline__ void acc2(unsigned int u, float& a0, float& a1) {
    half2_t h = __builtin_bit_cast(half2_t, u);
    a0 += (float)h[0];
    a1 += (float)h[1];
}

__device__ __forceinline__ unsigned pack2(float x, float y) {
    half2_t o;
    o[0] = (h16)x;
    o[1] = (h16)y;
    return __builtin_bit_cast(unsigned, o);
}

// ===========================================================================
// Partition edges into 64-node dst buckets, 8-way replicated cursors.
// Known floor (r5-r9): scattered-request pipe, ~66 µs. Unchanged.
// ===========================================================================
__global__ __launch_bounds__(256) void k_partition(const int* __restrict__ src,
                                                   const int* __restrict__ dst,
                                                   int* __restrict__ cnt,
                                                   int* __restrict__ buckets) {
    int rep = blockIdx.x & (NREP - 1);
    int i = blockIdx.x * blockDim.x + threadIdx.x;
    int stride = gridDim.x * blockDim.x;
    for (; i < N_EDGES; i += stride) {
        int s = src[i];
        int d = dst[i];
        int b = d >> 6;
        int pos = atomicAdd(&cnt[b * NREP + rep], 1);
        if (pos < SEG_CAP)
            buckets[(size_t)b * BK_STRIDE + rep * SEG_CAP + pos] = ((d & 63) << 17) | s;
    }
}

// ===========================================================================
// Merge the 8 segments of each bucket, sort by dstLocal in LDS, write back
// compacted + bucket-local rowptr [65]. Unchanged.
// ===========================================================================
__global__ __launch_bounds__(256) void k_bucket_sort(const int* __restrict__ cnt,
                                                     int* __restrict__ buckets,
                                                     int* __restrict__ rowptrL) {
    __shared__ int srt[BK_STRIDE];
    __shared__ int hist[BK_NODES];
    __shared__ int curs[BK_NODES];
    int b = blockIdx.x, t = threadIdx.x;
    int* gb = buckets + (size_t)b * BK_STRIDE;
    int c[NREP];
#pragma unroll
    for (int r = 0; r < NREP; ++r) {
        int x = cnt[b * NREP + r];
        c[r] = x < SEG_CAP ? x : SEG_CAP;
    }
    if (t < BK_NODES) hist[t] = 0;
    __syncthreads();
#pragma unroll
    for (int r = 0; r < NREP; ++r)
        for (int i = t; i < c[r]; i += 256)
            atomicAdd(&hist[gb[r * SEG_CAP + i] >> 17], 1);
    __syncthreads();
    if (t < 64) {
        int h = hist[t];
        int x = h;
        for (int off = 1; off < 64; off <<= 1) {
            int u = __shfl_up(x, off, 64);
            if (t >= off) x += u;
        }
        curs[t] = x - h;
        rowptrL[b * 65 + t] = x - h;
        if (t == 63) rowptrL[b * 65 + 64] = x;
    }
    __syncthreads();
#pragma unroll
    for (int r = 0; r < NREP; ++r)
        for (int i = t; i < c[r]; i += 256) {
            int rec = gb[r * SEG_CAP + i];
            int pos = atomicAdd(&curs[rec >> 17], 1);
            srt[pos] = rec;
        }
    __syncthreads();
    int n = 0;
#pragma unroll
    for (int r = 0; r < NREP; ++r) n += c[r];
    for (int i = t; i < n; i += 256) gb[i] = srt[i];
}

// ===========================================================================
// Aggregate (r7 form, at its L3-random-line floor ~160MB/layer). Unchanged.
// ===========================================================================
__global__ __launch_bounds__(256) void k_aggregate(const int* __restrict__ rowptrL,
                                                   const int* __restrict__ buckets,
                                                   const h16* __restrict__ H,
                                                   h16* __restrict__ Z) {
    const unsigned int* H2 = (const unsigned int*)H;
    unsigned int* Z2 = (unsigned int*)Z;
    int lane = threadIdx.x & 63;
    int half = lane >> 5, sub = lane & 31;
    int gwave = (blockIdx.x * 256 + threadIdx.x) >> 6;
    int nw = (gridDim.x * 256) >> 6;
    for (int i = gwave; i < N_NODES; i += nw) {
        int b = i >> 6, local = i & 63;
        int start = rowptrL[b * 65 + local], end = rowptrL[b * 65 + local + 1];
        const int* bk = buckets + (size_t)b * BK_STRIDE;
        float a0 = 0.f, a1 = 0.f;
        if (half == 0) acc2(H2[(size_t)i * 32 + sub], a0, a1);
        int j = start;
        for (; j + 4 <= end; j += 4) {
            int sA = bk[j + half] & 0x1FFFF;
            int sB = bk[j + 2 + half] & 0x1FFFF;
            unsigned int uA = H2[(size_t)sA * 32 + sub];
            unsigned int uB = H2[(size_t)sB * 32 + sub];
            acc2(uA, a0, a1);
            acc2(uB, a0, a1);
        }
        if (j + 1 < end) {
            int s = bk[j + half] & 0x1FFFF;
            acc2(H2[(size_t)s * 32 + sub], a0, a1);
            j += 2;
        }
        if (j < end && half == 0) {
            int s = bk[j] & 0x1FFFF;
            acc2(H2[(size_t)s * 32 + sub], a0, a1);
        }
        a0 += __shfl_xor(a0, 32, 64);
        a1 += __shfl_xor(a1, 32, 64);
        if (half == 0) Z2[(size_t)i * 32 + sub] = pack2(a0, a1);
    }
}

// ===========================================================================
// Weight prep (once per call): swizzle 7 64x64 fp32 matrices into fp16
// B-fragment order for mfma_f32_16x16x32_f16. Fragment f=((c*2+kc)*4+quad):
// element (n=lane&15, j) at WF[f*128 + n*8 + j] = W[kc*32+quad*8+j][16c+n].
// ===========================================================================
__global__ __launch_bounds__(256) void k_wprep(const float* __restrict__ Wq0,
                                               const float* __restrict__ Wq1,
                                               const float* __restrict__ Wq2,
                                               const float* __restrict__ Wq3,
                                               const float* __restrict__ Wq4,
                                               const float* __restrict__ Wq5,
                                               const float* __restrict__ Wq6,
                                               h16* __restrict__ WF) {
    const float* Ws[7] = {Wq0, Wq1, Wq2, Wq3, Wq4, Wq5, Wq6};
    const float* W = Ws[blockIdx.x];
    h16* dstW = WF + (size_t)blockIdx.x * 4096;
    int t = threadIdx.x;
#pragma unroll
    for (int i = 0; i < 16; ++i) {
        int s = t + 256 * i;           // coalesced source read
        int k = s >> 6, col = s & 63;
        int kc = k >> 5, quad = (k >> 3) & 3, j = k & 7;
        int c = col >> 4, n = col & 15;
        dstW[((c * 2 + kc) * 4 + quad) * 128 + n * 8 + j] = (h16)W[s];
    }
}

// ===========================================================================
// MFMA MLP (r10): 64-row tile, 4 waves, wave = 16 rows x 64 cols.
// A-frags: direct 16B global loads from fp16 Z (no LDS staging).
// B-frags: direct 16B global loads from pre-swizzled WF (L2 broadcast).
// LDS only for the wave-PRIVATE GEMM1->GEMM2 transpose + epilogue repack
// (stride-68 fp32 rows) -> zero __syncthreads.
// C/D: row=quad*4+reg, col=lane&15. A: [m=lane&15][k=quad*8+j]. B: mirror.
// ===========================================================================
__global__ __launch_bounds__(256) void k_mlp(const h16* __restrict__ WaF,
                                             const float* __restrict__ Ba,
                                             const h16* __restrict__ WbF,
                                             const float* __restrict__ Bb,
                                             const h16* __restrict__ Zin,
                                             h16* __restrict__ Hout) {
    __shared__ float sT[4 * 16 * TSTRIDE];
    int t = threadIdx.x;
    int w = t >> 6, lane = t & 63;
    int n16 = lane & 15, quad = lane >> 4;
    float* T = sT + w * 16 * TSTRIDE;
    int rbase = blockIdx.x * 64 + w * 16;

    // A-frags (lane's row = rbase + n16), k-chunks 0..31 / 32..63
    int arow = rbase + n16;
    int crow = arow < N_NODES ? arow : N_NODES - 1;
    const f16x8* zp = (const f16x8*)(Zin + (size_t)crow * HID + quad * 8);
    f16x8 a0 = zp[0];
    f16x8 a1 = zp[4];  // +32 elements

    // B-frags for both GEMMs (16B/lane, L2-resident)
    f16x8 bwa[4][2], bwb[4][2];
#pragma unroll
    for (int c = 0; c < 4; ++c)
#pragma unroll
        for (int kc = 0; kc < 2; ++kc) {
            int f = ((c * 2 + kc) * 4 + quad) * 128 + n16 * 8;
            bwa[c][kc] = *(const f16x8*)(WaF + f);
            bwb[c][kc] = *(const f16x8*)(WbF + f);
        }

    // GEMM1
    f32x4 acc[4];
#pragma unroll
    for (int c = 0; c < 4; ++c) {
        float bv = Ba[c * 16 + n16];
        acc[c] = (f32x4){bv, bv, bv, bv};
        acc[c] = __builtin_amdgcn_mfma_f32_16x16x32_f16(a0, bwa[c][0], acc[c], 0, 0, 0);
        acc[c] = __builtin_amdgcn_mfma_f32_16x16x32_f16(a1, bwa[c][1], acc[c], 0, 0, 0);
    }

    // T = relu(acc): C/D (row=quad*4+r, col=16c+n16) -> wave-private LDS
#pragma unroll
    for (int c = 0; c < 4; ++c)
#pragma unroll
        for (int r = 0; r < 4; ++r)
            T[(quad * 4 + r) * TSTRIDE + c * 16 + n16] = fmaxf(acc[c][r], 0.f);

    // GEMM2 A-frags: T[m=n16][k=kc*32+quad*8+j], cvt fp32->fp16
    f16x8 ta[2];
#pragma unroll
    for (int kc = 0; kc < 2; ++kc) {
        float4 p = *(const float4*)&T[n16 * TSTRIDE + kc * 32 + quad * 8];
        float4 q = *(const float4*)&T[n16 * TSTRIDE + kc * 32 + quad * 8 + 4];
        f16x8 v;
        v[0] = (h16)p.x; v[1] = (h16)p.y; v[2] = (h16)p.z; v[3] = (h16)p.w;
        v[4] = (h16)q.x; v[5] = (h16)q.y; v[6] = (h16)q.z; v[7] = (h16)q.w;
        ta[kc] = v;
    }

    // GEMM2
#pragma unroll
    for (int c = 0; c < 4; ++c) {
        float bv = Bb[c * 16 + n16];
        acc[c] = (f32x4){bv, bv, bv, bv};
        acc[c] = __builtin_amdgcn_mfma_f32_16x16x32_f16(ta[0], bwb[c][0], acc[c], 0, 0, 0);
        acc[c] = __builtin_amdgcn_mfma_f32_16x16x32_f16(ta[1], bwb[c][1], acc[c], 0, 0, 0);
    }

    // epilogue: relu -> T -> coalesced fp16 row stores (32B/lane)
#pragma unroll
    for (int c = 0; c < 4; ++c)
#pragma unroll
        for (int r = 0; r < 4; ++r)
            T[(quad * 4 + r) * TSTRIDE + c * 16 + n16] = fmaxf(acc[c][r], 0.f);
    {
        int rl = lane >> 2, seg = lane & 3;
        int row = rbase + rl;
        if (row < N_NODES) {
            const float* tr = &T[rl * TSTRIDE + seg * 16];
            f16x8 o0, o1;
#pragma unroll
            for (int i = 0; i < 8; ++i) {
                o0[i] = (h16)tr[i];
                o1[i] = (h16)tr[8 + i];
            }
            f16x8* dp = (f16x8*)(Hout + (size_t)row * HID + seg * 16);
            dp[0] = o0;
            dp[1] = o1;
        }
    }
}

// ===========================================================================
// MFMA input linear (r10): same structure, A from fp32 X (cvt), single GEMM.
// ===========================================================================
__global__ __launch_bounds__(256) void k_lin(const h16* __restrict__ W0F,
                                             const float* __restrict__ B,
                                             const float* __restrict__ Xin,
                                             h16* __restrict__ Hout) {
    __shared__ float sT[4 * 16 * TSTRIDE];
    int t = threadIdx.x;
    int w = t >> 6, lane = t & 63;
    int n16 = lane & 15, quad = lane >> 4;
    float* T = sT + w * 16 * TSTRIDE;
    int rbase = blockIdx.x * 64 + w * 16;

    int arow = rbase + n16;
    int crow = arow < N_NODES ? arow : N_NODES - 1;
    f16x8 a[2];
#pragma unroll
    for (int kc = 0; kc < 2; ++kc) {
        const float4* xp = (const float4*)(Xin + (size_t)crow * HID + kc * 32 + quad * 8);
        float4 p = xp[0], q = xp[1];
        f16x8 v;
        v[0] = (h16)p.x; v[1] = (h16)p.y; v[2] = (h16)p.z; v[3] = (h16)p.w;
        v[4] = (h16)q.x; v[5] = (h16)q.y; v[6] = (h16)q.z; v[7] = (h16)q.w;
        a[kc] = v;
    }

    f32x4 acc[4];
#pragma unroll
    for (int c = 0; c < 4; ++c) {
        float bv = B[c * 16 + n16];
        acc[c] = (f32x4){bv, bv, bv, bv};
#pragma unroll
        for (int kc = 0; kc < 2; ++kc) {
            f16x8 bw = *(const f16x8*)(W0F + ((c * 2 + kc) * 4 + quad) * 128 + n16 * 8);
            acc[c] = __builtin_amdgcn_mfma_f32_16x16x32_f16(a[kc], bw, acc[c], 0, 0, 0);
        }
    }

#pragma unroll
    for (int c = 0; c < 4; ++c)
#pragma unroll
        for (int r = 0; r < 4; ++r)
            T[(quad * 4 + r) * TSTRIDE + c * 16 + n16] = fmaxf(acc[c][r], 0.f);
    {
        int rl = lane >> 2, seg = lane & 3;
        int row = rbase + rl;
        if (row < N_NODES) {
            const float* tr = &T[rl * TSTRIDE + seg * 16];
            f16x8 o0, o1;
#pragma unroll
            for (int i = 0; i < 8; ++i) {
                o0[i] = (h16)tr[i];
                o1[i] = (h16)tr[8 + i];
            }
            f16x8* dp = (f16x8*)(Hout + (size_t)row * HID + seg * 16);
            dp[0] = o0;
            dp[1] = o1;
        }
    }
}

// ===========================================================================
// Fused mean-pool + readout (r9): one block per graph. Unchanged.
// ===========================================================================
__global__ __launch_bounds__(256) void k_poolfinal(const h16* __restrict__ H,
                                                   const int* __restrict__ batch,
                                                   const float* __restrict__ Wl,
                                                   const float* __restrict__ bl,
                                                   float* __restrict__ out) {
    __shared__ float sp[4 * HID];
    int g = blockIdx.x;
    int t = threadIdx.x;
    int lane = t & 63, w = t >> 6;
    int lo = 0, hi = N_NODES;
    while (lo < hi) { int m = (lo + hi) >> 1; if (batch[m] < g) lo = m + 1; else hi = m; }
    int start = lo;
    hi = N_NODES;
    while (lo < hi) { int m = (lo + hi) >> 1; if (batch[m] < g + 1) lo = m + 1; else hi = m; }
    int end = lo;
    float s = 0.f;
    for (int r = start + w; r < end; r += 4) s += (float)H[(size_t)r * HID + lane];
    sp[w * HID + lane] = s;
    __syncthreads();
    if (t < HID) {
        float tot = sp[t] + sp[HID + t] + sp[2 * HID + t] + sp[3 * HID + t];
        float c = (end > start) ? (float)(end - start) : 1.0f;
        sp[t] = tot / c;
    }
    __syncthreads();
    if (t < OUT_CH) {
        float acc = bl[t];
#pragma unroll
        for (int k = 0; k < HID; ++k) acc += sp[k] * Wl[k * OUT_CH + t];
        out[g * OUT_CH + t] = acc;
    }
}

extern "C" void kernel_launch(void* const* d_in, const int* in_sizes, int n_in,
                              void* d_out, int out_size, void* d_ws, size_t ws_size,
                              hipStream_t stream) {
    const float* x     = (const float*)d_in[0];
    const int*   edge  = (const int*)d_in[1];   // [2][N_EDGES] int32
    const int*   batch = (const int*)d_in[2];   // [N_NODES] int32 (sorted)
    const float* W0  = (const float*)d_in[3];
    const float* b0  = (const float*)d_in[4];
    const float* W1a = (const float*)d_in[5];
    const float* b1a = (const float*)d_in[6];
    const float* W1b = (const float*)d_in[7];
    const float* b1b = (const float*)d_in[8];
    const float* W2a = (const float*)d_in[9];
    const float* b2a = (const float*)d_in[10];
    const float* W2b = (const float*)d_in[11];
    const float* b2b = (const float*)d_in[12];
    const float* W3a = (const float*)d_in[13];
    const float* b3a = (const float*)d_in[14];
    const float* W3b = (const float*)d_in[15];
    const float* b3b = (const float*)d_in[16];
    const float* Wl  = (const float*)d_in[17];
    const float* bl  = (const float*)d_in[18];
    float* out = (float*)d_out;

    const int* src = edge;
    const int* dst = edge + N_EDGES;

    // Workspace: HA(fp16) | Z(fp16) | cnt | rowptrL | buckets | WF(fp16)
    h16* HA = (h16*)d_ws;
    h16* Z  = HA + (size_t)N_NODES * HID;
    int* cnt     = (int*)(Z + (size_t)N_NODES * HID);
    int* rowptrL = cnt + NBUCKET * NREP;
    int* buckets = rowptrL + NBUCKET * 65;
    h16* WF      = (h16*)(buckets + (size_t)NBUCKET * BK_STRIDE);
    h16* W0F = WF;               // order: W0, W1a, W1b, W2a, W2b, W3a, W3b
    h16* W1aF = WF + 4096 * 1;
    h16* W1bF = WF + 4096 * 2;
    h16* W2aF = WF + 4096 * 3;
    h16* W2bF = WF + 4096 * 4;
    h16* W3aF = WF + 4096 * 5;
    h16* W3bF = WF + 4096 * 6;

    hipMemsetAsync(cnt, 0, NBUCKET * NREP * sizeof(int), stream);
    k_partition<<<4096, 256, 0, stream>>>(src, dst, cnt, buckets);
    k_bucket_sort<<<NBUCKET, 256, 0, stream>>>(cnt, buckets, rowptrL);
    k_wprep<<<7, 256, 0, stream>>>(W0, W1a, W1b, W2a, W2b, W3a, W3b, WF);

    k_lin<<<TILE1, 256, 0, stream>>>(W0F, b0, x, HA);

    k_aggregate<<<4096, 256, 0, stream>>>(rowptrL, buckets, HA, Z);
    k_mlp<<<TILE1, 256, 0, stream>>>(W1aF, b1a, W1bF, b1b, Z, HA);

    k_aggregate<<<4096, 256, 0, stream>>>(rowptrL, buckets, HA, Z);
    k_mlp<<<TILE1, 256, 0, stream>>>(W2aF, b2a, W2bF, b2b, Z, HA);

    k_aggregate<<<4096, 256, 0, stream>>>(rowptrL, buckets, HA, Z);
    k_mlp<<<TILE1, 256, 0, stream>>>(W3aF, b3a, W3bF, b3b, Z, HA);

    k_poolfinal<<<N_GRAPHS, 256, 0, stream>>>(HA, batch, Wl, bl, out);
}

// Round 11
// 364.163 us; speedup vs baseline: 1.2467x; 1.0664x over previous
//
#include <hip/hip_runtime.h>
#include <hip/hip_fp16.h>

#define N_NODES 100000
#define N_EDGES 1250000
#define HID 64
#define N_GRAPHS 512
#define OUT_CH 16

#define BK_NODES 64
#define NBUCKET ((N_NODES + BK_NODES - 1) / BK_NODES)  // 1563
#define NREP 8          // cursor replicas
#define SEG_CAP 192     // per-segment cap: mean 100, sigma 9.4 -> +9.8σ
#define BK_STRIDE (NREP * SEG_CAP)  // 1536 ints per bucket
#define TILE1 ((N_NODES + 63) / 64)  // 1563 blocks, 64-row MFMA tiles
#define TSTRIDE 68      // LDS T row stride (floats): 16B-aligned, writes 2-way

typedef _Float16 h16;
typedef _Float16 half2_t __attribute__((ext_vector_type(2)));
typedef _Float16 f16x8 __attribute__((ext_vector_type(8)));
typedef float f32x4 __attribute__((ext_vector_type(4)));

__device__ __forceinline__ void acc2(unsigned int u, float& a0, float& a1) {
    half2_t h = __builtin_bit_cast(half2_t, u);
    a0 += (float)h[0];
    a1 += (float)h[1];
}

__device__ __forceinline__ unsigned pack2(float x, float y) {
    half2_t o;
    o[0] = (h16)x;
    o[1] = (h16)y;
    return __builtin_bit_cast(unsigned, o);
}

// ===========================================================================
// Partition edges into 64-node dst buckets, 8-way replicated cursors.
// Known floor (r5-r10): scattered-request pipe, ~66 µs. Unchanged.
// ===========================================================================
__global__ __launch_bounds__(256) void k_partition(const int* __restrict__ src,
                                                   const int* __restrict__ dst,
                                                   int* __restrict__ cnt,
                                                   int* __restrict__ buckets) {
    int rep = blockIdx.x & (NREP - 1);
    int i = blockIdx.x * blockDim.x + threadIdx.x;
    int stride = gridDim.x * blockDim.x;
    for (; i < N_EDGES; i += stride) {
        int s = src[i];
        int d = dst[i];
        int b = d >> 6;
        int pos = atomicAdd(&cnt[b * NREP + rep], 1);
        if (pos < SEG_CAP)
            buckets[(size_t)b * BK_STRIDE + rep * SEG_CAP + pos] = ((d & 63) << 17) | s;
    }
}

// ===========================================================================
// Merge the 8 segments of each bucket, sort by dstLocal in LDS, write back
// compacted + bucket-local rowptr [65]. Unchanged.
// ===========================================================================
__global__ __launch_bounds__(256) void k_bucket_sort(const int* __restrict__ cnt,
                                                     int* __restrict__ buckets,
                                                     int* __restrict__ rowptrL) {
    __shared__ int srt[BK_STRIDE];
    __shared__ int hist[BK_NODES];
    __shared__ int curs[BK_NODES];
    int b = blockIdx.x, t = threadIdx.x;
    int* gb = buckets + (size_t)b * BK_STRIDE;
    int c[NREP];
#pragma unroll
    for (int r = 0; r < NREP; ++r) {
        int x = cnt[b * NREP + r];
        c[r] = x < SEG_CAP ? x : SEG_CAP;
    }
    if (t < BK_NODES) hist[t] = 0;
    __syncthreads();
#pragma unroll
    for (int r = 0; r < NREP; ++r)
        for (int i = t; i < c[r]; i += 256)
            atomicAdd(&hist[gb[r * SEG_CAP + i] >> 17], 1);
    __syncthreads();
    if (t < 64) {
        int h = hist[t];
        int x = h;
        for (int off = 1; off < 64; off <<= 1) {
            int u = __shfl_up(x, off, 64);
            if (t >= off) x += u;
        }
        curs[t] = x - h;
        rowptrL[b * 65 + t] = x - h;
        if (t == 63) rowptrL[b * 65 + 64] = x;
    }
    __syncthreads();
#pragma unroll
    for (int r = 0; r < NREP; ++r)
        for (int i = t; i < c[r]; i += 256) {
            int rec = gb[r * SEG_CAP + i];
            int pos = atomicAdd(&curs[rec >> 17], 1);
            srt[pos] = rec;
        }
    __syncthreads();
    int n = 0;
#pragma unroll
    for (int r = 0; r < NREP; ++r) n += c[r];
    for (int i = t; i < n; i += 256) gb[i] = srt[i];
}

// ===========================================================================
// Aggregate r11: 8-edge unroll -> 4 independent gathers in flight per
// half-wave (2x r7). Hypothesis: latency x parallelism bound (~32 waves/CU
// x 2 outstanding = 5 TB/s ceiling vs 2.6 measured) -> deeper MLP helps.
// ===========================================================================
__global__ __launch_bounds__(256) void k_aggregate(const int* __restrict__ rowptrL,
                                                   const int* __restrict__ buckets,
                                                   const h16* __restrict__ H,
                                                   h16* __restrict__ Z) {
    const unsigned int* H2 = (const unsigned int*)H;
    unsigned int* Z2 = (unsigned int*)Z;
    int lane = threadIdx.x & 63;
    int half = lane >> 5, sub = lane & 31;
    int gwave = (blockIdx.x * 256 + threadIdx.x) >> 6;
    int nw = (gridDim.x * 256) >> 6;
    for (int i = gwave; i < N_NODES; i += nw) {
        int b = i >> 6, local = i & 63;
        int start = rowptrL[b * 65 + local], end = rowptrL[b * 65 + local + 1];
        const int* bk = buckets + (size_t)b * BK_STRIDE;
        float a0 = 0.f, a1 = 0.f;
        if (half == 0) acc2(H2[(size_t)i * 32 + sub], a0, a1);
        int j = start;
        for (; j + 8 <= end; j += 8) {
            int s0 = bk[j + half] & 0x1FFFF;
            int s1 = bk[j + 2 + half] & 0x1FFFF;
            int s2 = bk[j + 4 + half] & 0x1FFFF;
            int s3 = bk[j + 6 + half] & 0x1FFFF;
            unsigned int u0 = H2[(size_t)s0 * 32 + sub];
            unsigned int u1 = H2[(size_t)s1 * 32 + sub];
            unsigned int u2 = H2[(size_t)s2 * 32 + sub];
            unsigned int u3 = H2[(size_t)s3 * 32 + sub];
            acc2(u0, a0, a1);
            acc2(u1, a0, a1);
            acc2(u2, a0, a1);
            acc2(u3, a0, a1);
        }
        if (j + 4 <= end) {
            int s0 = bk[j + half] & 0x1FFFF;
            int s1 = bk[j + 2 + half] & 0x1FFFF;
            unsigned int u0 = H2[(size_t)s0 * 32 + sub];
            unsigned int u1 = H2[(size_t)s1 * 32 + sub];
            acc2(u0, a0, a1);
            acc2(u1, a0, a1);
            j += 4;
        }
        if (j + 1 < end) {
            int s = bk[j + half] & 0x1FFFF;
            acc2(H2[(size_t)s * 32 + sub], a0, a1);
            j += 2;
        }
        if (j < end && half == 0) {
            int s = bk[j] & 0x1FFFF;
            acc2(H2[(size_t)s * 32 + sub], a0, a1);
        }
        a0 += __shfl_xor(a0, 32, 64);
        a1 += __shfl_xor(a1, 32, 64);
        if (half == 0) Z2[(size_t)i * 32 + sub] = pack2(a0, a1);
    }
}

// ===========================================================================
// Weight prep (once per call): swizzle 7 64x64 fp32 matrices into fp16
// B-fragment order for mfma_f32_16x16x32_f16. Unchanged.
// ===========================================================================
__global__ __launch_bounds__(256) void k_wprep(const float* __restrict__ Wq0,
                                               const float* __restrict__ Wq1,
                                               const float* __restrict__ Wq2,
                                               const float* __restrict__ Wq3,
                                               const float* __restrict__ Wq4,
                                               const float* __restrict__ Wq5,
                                               const float* __restrict__ Wq6,
                                               h16* __restrict__ WF) {
    const float* Ws[7] = {Wq0, Wq1, Wq2, Wq3, Wq4, Wq5, Wq6};
    const float* W = Ws[blockIdx.x];
    h16* dstW = WF + (size_t)blockIdx.x * 4096;
    int t = threadIdx.x;
#pragma unroll
    for (int i = 0; i < 16; ++i) {
        int s = t + 256 * i;
        int k = s >> 6, col = s & 63;
        int kc = k >> 5, quad = (k >> 3) & 3, j = k & 7;
        int c = col >> 4, n = col & 15;
        dstW[((c * 2 + kc) * 4 + quad) * 128 + n * 8 + j] = (h16)W[s];
    }
}

// ===========================================================================
// MFMA MLP (r10, proven): 64-row tile, wave = 16 rows x 64 cols, direct
// global A/B-frag loads, wave-private LDS transpose, zero __syncthreads.
// ===========================================================================
__global__ __launch_bounds__(256) void k_mlp(const h16* __restrict__ WaF,
                                             const float* __restrict__ Ba,
                                             const h16* __restrict__ WbF,
                                             const float* __restrict__ Bb,
                                             const h16* __restrict__ Zin,
                                             h16* __restrict__ Hout) {
    __shared__ float sT[4 * 16 * TSTRIDE];
    int t = threadIdx.x;
    int w = t >> 6, lane = t & 63;
    int n16 = lane & 15, quad = lane >> 4;
    float* T = sT + w * 16 * TSTRIDE;
    int rbase = blockIdx.x * 64 + w * 16;

    int arow = rbase + n16;
    int crow = arow < N_NODES ? arow : N_NODES - 1;
    const f16x8* zp = (const f16x8*)(Zin + (size_t)crow * HID + quad * 8);
    f16x8 a0 = zp[0];
    f16x8 a1 = zp[4];

    f16x8 bwa[4][2], bwb[4][2];
#pragma unroll
    for (int c = 0; c < 4; ++c)
#pragma unroll
        for (int kc = 0; kc < 2; ++kc) {
            int f = ((c * 2 + kc) * 4 + quad) * 128 + n16 * 8;
            bwa[c][kc] = *(const f16x8*)(WaF + f);
            bwb[c][kc] = *(const f16x8*)(WbF + f);
        }

    f32x4 acc[4];
#pragma unroll
    for (int c = 0; c < 4; ++c) {
        float bv = Ba[c * 16 + n16];
        acc[c] = (f32x4){bv, bv, bv, bv};
        acc[c] = __builtin_amdgcn_mfma_f32_16x16x32_f16(a0, bwa[c][0], acc[c], 0, 0, 0);
        acc[c] = __builtin_amdgcn_mfma_f32_16x16x32_f16(a1, bwa[c][1], acc[c], 0, 0, 0);
    }

#pragma unroll
    for (int c = 0; c < 4; ++c)
#pragma unroll
        for (int r = 0; r < 4; ++r)
            T[(quad * 4 + r) * TSTRIDE + c * 16 + n16] = fmaxf(acc[c][r], 0.f);

    f16x8 ta[2];
#pragma unroll
    for (int kc = 0; kc < 2; ++kc) {
        float4 p = *(const float4*)&T[n16 * TSTRIDE + kc * 32 + quad * 8];
        float4 q = *(const float4*)&T[n16 * TSTRIDE + kc * 32 + quad * 8 + 4];
        f16x8 v;
        v[0] = (h16)p.x; v[1] = (h16)p.y; v[2] = (h16)p.z; v[3] = (h16)p.w;
        v[4] = (h16)q.x; v[5] = (h16)q.y; v[6] = (h16)q.z; v[7] = (h16)q.w;
        ta[kc] = v;
    }

#pragma unroll
    for (int c = 0; c < 4; ++c) {
        float bv = Bb[c * 16 + n16];
        acc[c] = (f32x4){bv, bv, bv, bv};
        acc[c] = __builtin_amdgcn_mfma_f32_16x16x32_f16(ta[0], bwb[c][0], acc[c], 0, 0, 0);
        acc[c] = __builtin_amdgcn_mfma_f32_16x16x32_f16(ta[1], bwb[c][1], acc[c], 0, 0, 0);
    }

#pragma unroll
    for (int c = 0; c < 4; ++c)
#pragma unroll
        for (int r = 0; r < 4; ++r)
            T[(quad * 4 + r) * TSTRIDE + c * 16 + n16] = fmaxf(acc[c][r], 0.f);
    {
        int rl = lane >> 2, seg = lane & 3;
        int row = rbase + rl;
        if (row < N_NODES) {
            const float* tr = &T[rl * TSTRIDE + seg * 16];
            f16x8 o0, o1;
#pragma unroll
            for (int i = 0; i < 8; ++i) {
                o0[i] = (h16)tr[i];
                o1[i] = (h16)tr[8 + i];
            }
            f16x8* dp = (f16x8*)(Hout + (size_t)row * HID + seg * 16);
            dp[0] = o0;
            dp[1] = o1;
        }
    }
}

// ===========================================================================
// MFMA input linear (r10, proven). Unchanged.
// ===========================================================================
__global__ __launch_bounds__(256) void k_lin(const h16* __restrict__ W0F,
                                             const float* __restrict__ B,
                                             const float* __restrict__ Xin,
                                             h16* __restrict__ Hout) {
    __shared__ float sT[4 * 16 * TSTRIDE];
    int t = threadIdx.x;
    int w = t >> 6, lane = t & 63;
    int n16 = lane & 15, quad = lane >> 4;
    float* T = sT + w * 16 * TSTRIDE;
    int rbase = blockIdx.x * 64 + w * 16;

    int arow = rbase + n16;
    int crow = arow < N_NODES ? arow : N_NODES - 1;
    f16x8 a[2];
#pragma unroll
    for (int kc = 0; kc < 2; ++kc) {
        const float4* xp = (const float4*)(Xin + (size_t)crow * HID + kc * 32 + quad * 8);
        float4 p = xp[0], q = xp[1];
        f16x8 v;
        v[0] = (h16)p.x; v[1] = (h16)p.y; v[2] = (h16)p.z; v[3] = (h16)p.w;
        v[4] = (h16)q.x; v[5] = (h16)q.y; v[6] = (h16)q.z; v[7] = (h16)q.w;
        a[kc] = v;
    }

    f32x4 acc[4];
#pragma unroll
    for (int c = 0; c < 4; ++c) {
        float bv = B[c * 16 + n16];
        acc[c] = (f32x4){bv, bv, bv, bv};
#pragma unroll
        for (int kc = 0; kc < 2; ++kc) {
            f16x8 bw = *(const f16x8*)(W0F + ((c * 2 + kc) * 4 + quad) * 128 + n16 * 8);
            acc[c] = __builtin_amdgcn_mfma_f32_16x16x32_f16(a[kc], bw, acc[c], 0, 0, 0);
        }
    }

#pragma unroll
    for (int c = 0; c < 4; ++c)
#pragma unroll
        for (int r = 0; r < 4; ++r)
            T[(quad * 4 + r) * TSTRIDE + c * 16 + n16] = fmaxf(acc[c][r], 0.f);
    {
        int rl = lane >> 2, seg = lane & 3;
        int row = rbase + rl;
        if (row < N_NODES) {
            const float* tr = &T[rl * TSTRIDE + seg * 16];
            f16x8 o0, o1;
#pragma unroll
            for (int i = 0; i < 8; ++i) {
                o0[i] = (h16)tr[i];
                o1[i] = (h16)tr[8 + i];
            }
            f16x8* dp = (f16x8*)(Hout + (size_t)row * HID + seg * 16);
            dp[0] = o0;
            dp[1] = o1;
        }
    }
}

// ===========================================================================
// Fused mean-pool + readout: one block per graph. Unchanged.
// ===========================================================================
__global__ __launch_bounds__(256) void k_poolfinal(const h16* __restrict__ H,
                                                   const int* __restrict__ batch,
                                                   const float* __restrict__ Wl,
                                                   const float* __restrict__ bl,
                                                   float* __restrict__ out) {
    __shared__ float sp[4 * HID];
    int g = blockIdx.x;
    int t = threadIdx.x;
    int lane = t & 63, w = t >> 6;
    int lo = 0, hi = N_NODES;
    while (lo < hi) { int m = (lo + hi) >> 1; if (batch[m] < g) lo = m + 1; else hi = m; }
    int start = lo;
    hi = N_NODES;
    while (lo < hi) { int m = (lo + hi) >> 1; if (batch[m] < g + 1) lo = m + 1; else hi = m; }
    int end = lo;
    float s = 0.f;
    for (int r = start + w; r < end; r += 4) s += (float)H[(size_t)r * HID + lane];
    sp[w * HID + lane] = s;
    __syncthreads();
    if (t < HID) {
        float tot = sp[t] + sp[HID + t] + sp[2 * HID + t] + sp[3 * HID + t];
        float c = (end > start) ? (float)(end - start) : 1.0f;
        sp[t] = tot / c;
    }
    __syncthreads();
    if (t < OUT_CH) {
        float acc = bl[t];
#pragma unroll
        for (int k = 0; k < HID; ++k) acc += sp[k] * Wl[k * OUT_CH + t];
        out[g * OUT_CH + t] = acc;
    }
}

extern "C" void kernel_launch(void* const* d_in, const int* in_sizes, int n_in,
                              void* d_out, int out_size, void* d_ws, size_t ws_size,
                              hipStream_t stream) {
    const float* x     = (const float*)d_in[0];
    const int*   edge  = (const int*)d_in[1];   // [2][N_EDGES] int32
    const int*   batch = (const int*)d_in[2];   // [N_NODES] int32 (sorted)
    const float* W0  = (const float*)d_in[3];
    const float* b0  = (const float*)d_in[4];
    const float* W1a = (const float*)d_in[5];
    const float* b1a = (const float*)d_in[6];
    const float* W1b = (const float*)d_in[7];
    const float* b1b = (const float*)d_in[8];
    const float* W2a = (const float*)d_in[9];
    const float* b2a = (const float*)d_in[10];
    const float* W2b = (const float*)d_in[11];
    const float* b2b = (const float*)d_in[12];
    const float* W3a = (const float*)d_in[13];
    const float* b3a = (const float*)d_in[14];
    const float* W3b = (const float*)d_in[15];
    const float* b3b = (const float*)d_in[16];
    const float* Wl  = (const float*)d_in[17];
    const float* bl  = (const float*)d_in[18];
    float* out = (float*)d_out;

    const int* src = edge;
    const int* dst = edge + N_EDGES;

    // Workspace: HA(fp16) | Z(fp16) | cnt | rowptrL | buckets | WF(fp16)
    h16* HA = (h16*)d_ws;
    h16* Z  = HA + (size_t)N_NODES * HID;
    int* cnt     = (int*)(Z + (size_t)N_NODES * HID);
    int* rowptrL = cnt + NBUCKET * NREP;
    int* buckets = rowptrL + NBUCKET * 65;
    h16* WF      = (h16*)(buckets + (size_t)NBUCKET * BK_STRIDE);
    h16* W0F = WF;               // order: W0, W1a, W1b, W2a, W2b, W3a, W3b
    h16* W1aF = WF + 4096 * 1;
    h16* W1bF = WF + 4096 * 2;
    h16* W2aF = WF + 4096 * 3;
    h16* W2bF = WF + 4096 * 4;
    h16* W3aF = WF + 4096 * 5;
    h16* W3bF = WF + 4096 * 6;

    hipMemsetAsync(cnt, 0, NBUCKET * NREP * sizeof(int), stream);
    k_partition<<<4096, 256, 0, stream>>>(src, dst, cnt, buckets);
    k_bucket_sort<<<NBUCKET, 256, 0, stream>>>(cnt, buckets, rowptrL);
    k_wprep<<<7, 256, 0, stream>>>(W0, W1a, W1b, W2a, W2b, W3a, W3b, WF);

    k_lin<<<TILE1, 256, 0, stream>>>(W0F, b0, x, HA);

    k_aggregate<<<4096, 256, 0, stream>>>(rowptrL, buckets, HA, Z);
    k_mlp<<<TILE1, 256, 0, stream>>>(W1aF, b1a, W1bF, b1b, Z, HA);

    k_aggregate<<<4096, 256, 0, stream>>>(rowptrL, buckets, HA, Z);
    k_mlp<<<TILE1, 256, 0, stream>>>(W2aF, b2a, W2bF, b2b, Z, HA);

    k_aggregate<<<4096, 256, 0, stream>>>(rowptrL, buckets, HA, Z);
    k_mlp<<<TILE1, 256, 0, stream>>>(W3aF, b3a, W3bF, b3b, Z, HA);

    k_poolfinal<<<N_GRAPHS, 256, 0, stream>>>(HA, batch, Wl, bl, out);
}